// Round 4
// baseline (493.880 us; speedup 1.0000x reference)
//
#include <hip/hip_runtime.h>
#include <math.h>

// Problem constants
#define NM 20301            // mesh points
#define TT 4096             // time steps
#define NC 128              // t-chunks (R4: 64->128, doubles block-level TLP)
#define CH 32               // steps per chunk = TT/NC
#define NBLK 80             // 256-thread n-kernels (density / senter)
#define SBLK 20             // states blocks in n (1024 n per block, 4/thread)
#define NPROW (SBLK * 4)    // 80 per-wave partial rows (speculative)
#define NROWS (NPROW + 80)  // + 80 patch correction rows (one per bx,wv)
#define TPH 16              // t-phase width for fused reduce
#define NPH (CH / TPH)      // 2 phases per chunk
#define LOG2E_K 1442.69504f // 1000 * log2(e)  (temp = 0.001)

// Fused soft-relay step: one rcp instead of two sigmoids.
__device__ __forceinline__ void relay_step(float ka, float kb, float ku,
                                           float& aa, float& bb) {
    float z1 = fminf(ka - ku, 63.f);
    float z2 = fminf(ku - kb, 63.f);
    float e1 = __builtin_amdgcn_exp2f(z1);
    float e2 = __builtin_amdgcn_exp2f(z2);
    float p1 = 1.f + e1, p2 = 1.f + e2;
    float r  = __builtin_amdgcn_rcpf(p1 * p2);
    aa = (e2 - e1) * r;
    bb = (e1 * e2) * r;
}

__device__ __forceinline__ float wave_reduce_sum(float w) {
    #pragma unroll
    for (int off = 32; off > 0; off >>= 1)
        w += __shfl_down(w, off, 64);
    return w;
}

// ---------------- density MLP: [N,2] -> 16 -> 16 -> 16 -> 1 ----------------
__global__ __launch_bounds__(256) void density_kernel(
    const float* __restrict__ alpha, const float* __restrict__ beta,
    const float* __restrict__ w1, const float* __restrict__ b1,
    const float* __restrict__ w2, const float* __restrict__ b2,
    const float* __restrict__ w3, const float* __restrict__ b3,
    const float* __restrict__ w4, const float* __restrict__ b4,
    float* __restrict__ density_out, float* __restrict__ densum_parts)
{
    int n = blockIdx.x * 256 + threadIdx.x;
    bool valid = n < NM;
    int nn = valid ? n : NM - 1;
    float a = alpha[nn], b = beta[nn];

    float h1[16], h2[16], h3[16];
    #pragma unroll
    for (int j = 0; j < 16; j++) {
        float v = fmaf(a, w1[j], fmaf(b, w1[16 + j], b1[j]));
        h1[j] = fmaxf(v, 0.f);
    }
    #pragma unroll
    for (int j = 0; j < 16; j++) {
        float v = b2[j];
        #pragma unroll
        for (int k = 0; k < 16; k++) v = fmaf(h1[k], w2[k * 16 + j], v);
        h2[j] = fmaxf(v, 0.f);
    }
    #pragma unroll
    for (int j = 0; j < 16; j++) {
        float v = b3[j];
        #pragma unroll
        for (int k = 0; k < 16; k++) v = fmaf(h2[k], w3[k * 16 + j], v);
        h3[j] = fmaxf(v, 0.f);
    }
    float v = b4[0];
    #pragma unroll
    for (int k = 0; k < 16; k++) v = fmaf(h3[k], w4[k], v);
    float d = 1.f / (1.f + __expf(-v));

    if (valid) density_out[n] = d;
    float wsum = wave_reduce_sum(valid ? d : 0.f);
    __shared__ float ws_[4];
    if ((threadIdx.x & 63) == 0) ws_[threadIdx.x >> 6] = wsum;
    __syncthreads();
    if (threadIdx.x == 0)
        densum_parts[blockIdx.x] = ws_[0] + ws_[1] + ws_[2] + ws_[3];
}

// ---- states pass: speculative affine recurrence, barrier/fence-free -------
// Tracks s_t = A_t + B_t * s_enter with s_enter unknown; B hits exact 0 at
// the first hard saturation (e underflows), after which states[t] = A_t is
// final. R4: (1) 128 chunks of 32 steps -> 2560 blocks (10/CU nominal, 8
// resident) for 2x stream-level parallelism and half the serial chain;
// (2) fast path removed -- __any(near) over 256 hysterons/wave was ~always
// true, so it was pure overhead (exact relay everywhere also tightens
// accuracy); (3) non-temporal states stores -- no kernel ever reads states.
__global__ __launch_bounds__(256) void states_spec_kernel(
    const float* __restrict__ x, const float* __restrict__ alpha,
    const float* __restrict__ beta, const float* __restrict__ density,
    float* __restrict__ states, float* __restrict__ partials,
    float* __restrict__ Acomp, float* __restrict__ Bcomp)
{
    __shared__ float xs[CH];
    __shared__ float tile[4 * 64 * (TPH + 1)];   // 17408 B

    int tid = threadIdx.x;
    int c = blockIdx.y;
    if (tid < CH) xs[tid] = x[c * CH + tid] * LOG2E_K;

    int n0 = blockIdx.x * 1024 + tid;
    float A[4], B[4], d[4], ka[4], kb[4];
    bool v[4];
    #pragma unroll
    for (int q = 0; q < 4; q++) {
        int n = n0 + q * 256;
        v[q] = n < NM;
        int nn = v[q] ? n : NM - 1;
        ka[q] = alpha[nn] * LOG2E_K;
        kb[q] = beta[nn] * LOG2E_K;
        d[q]  = v[q] ? density[n] : 0.f;
        A[q] = 0.f; B[q] = 1.f;
    }
    __syncthreads();   // once, for xs[]; hot loop below is barrier-free

    int wv = tid >> 6, ln = tid & 63;
    int tl = ln & 15, h = ln >> 4;
    float* wtile = &tile[wv * 64 * (TPH + 1)];
    float* tslot = &wtile[ln * (TPH + 1)];
    float* rp    = states + (size_t)c * CH * NM + n0;   // one vaddr, 4 chains
    size_t prow  = (size_t)(blockIdx.x * 4 + wv) * TT + c * CH;

    #pragma unroll 1
    for (int p = 0; p < NPH; p++) {
        float xr[TPH];
        #pragma unroll
        for (int j = 0; j < TPH; j++) xr[j] = xs[p * TPH + j];
        #pragma unroll
        for (int j = 0; j < TPH; j++) {
            float u = xr[j];
            #pragma unroll
            for (int q = 0; q < 4; q++) {
                float aa, bb;
                relay_step(ka[q], kb[q], u, aa, bb);
                A[q] = fmaf(bb, A[q], aa);
                B[q] *= bb;
                if (v[q]) __builtin_nontemporal_store(A[q], rp + q * 256);
            }
            rp += NM;
            tslot[j] = fmaf(d[0], A[0], fmaf(d[1], A[1],
                       fmaf(d[2], A[2], d[3] * A[3])));
        }
        // wait own LDS writes only (global stores stay in flight)
        asm volatile("s_waitcnt lgkmcnt(0)" ::: "memory");
        float acc = 0.f;
        #pragma unroll
        for (int k = 0; k < TPH; k++)
            acc += wtile[(h * 16 + k) * (TPH + 1) + tl];  // 2-way banks, free
        acc += __shfl_xor(acc, 16, 64);       // fold 4 n-groups
        acc += __shfl_xor(acc, 32, 64);
        if (ln < TPH) partials[prow + p * TPH + ln] = acc;
        // WAR guard before next phase overwrites the tile
        asm volatile("s_waitcnt lgkmcnt(0)" ::: "memory");
    }

    // publish end-of-chunk composite (plain stores; consumed next launch)
    #pragma unroll
    for (int q = 0; q < 4; q++) {
        if (v[q]) {
            Acomp[(size_t)c * NM + n0 + q * 256] = A[q];
            Bcomp[(size_t)c * NM + n0 + q * 256] = B[q];
        }
    }
}

// ---- senter scan: s_enter for every chunk, load-latency-free --------------
// Only the 128-step fmaf chain is serial; the 256 composite loads per thread
// are independent. Double-buffered batches of 16 chunks keep the chain off
// the load-latency critical path. Fully unrolled -> compile-time indices
// (runtime-indexed register arrays would spill to scratch).
__global__ __launch_bounds__(256) void senter_kernel(
    const float* __restrict__ init_raw,
    const float* __restrict__ Acomp, const float* __restrict__ Bcomp,
    float* __restrict__ senter)
{
    int n = blockIdx.x * 256 + threadIdx.x;
    if (n >= NM) return;
    float s = tanhf(init_raw[n]);
    float a0[16], b0[16], a1[16], b1[16];
    #pragma unroll
    for (int k = 0; k < 16; k++) {
        a0[k] = Acomp[(size_t)k * NM + n];
        b0[k] = Bcomp[(size_t)k * NM + n];
    }
    #pragma unroll
    for (int bt = 0; bt < 8; bt++) {
        if (bt + 1 < 8) {       // prefetch next batch while chaining this one
            #pragma unroll
            for (int k = 0; k < 16; k++) {
                size_t idx = (size_t)((bt + 1) * 16 + k) * NM + n;
                if (bt & 1) { a0[k] = Acomp[idx]; b0[k] = Bcomp[idx]; }
                else        { a1[k] = Acomp[idx]; b1[k] = Bcomp[idx]; }
            }
        }
        #pragma unroll
        for (int k = 0; k < 16; k++) {
            senter[(size_t)(bt * 16 + k) * NM + n] = s;
            if (bt & 1) s = fmaf(b1[k], s, a1[k]);
            else        s = fmaf(b0[k], s, a0[k]);
        }
    }
}

// ---- patch: parallel prefix fixup, one block per (n-block, chunk) ---------
// 2560 blocks -- no serial chunk loop, no cross-wave atomics. Replays the
// chunk prefix with the exact relay from s_enter until B underflows to
// exact 0 for the whole wave (~10 steps), patches states entries that were
// still s_enter-dependent, and keeps the per-step m correction
// (sum_n d*Bf*s_enter) in a per-lane register: after the butterfly reduce,
// lane j keeps step j's value, so the wave's correction row-slice is one
// coalesced store (zeros beyond the break included -- required, ws is
// re-poisoned between iterations).
__global__ __launch_bounds__(256) void patch_kernel(
    const float* __restrict__ x, const float* __restrict__ alpha,
    const float* __restrict__ beta, const float* __restrict__ density,
    const float* __restrict__ senter,
    float* __restrict__ states, float* __restrict__ partials)
{
    __shared__ float xsl[CH];
    int tid = threadIdx.x;
    int c = blockIdx.y, bx = blockIdx.x;
    if (tid < CH) xsl[tid] = x[c * CH + tid] * LOG2E_K;

    int n0 = bx * 1024 + tid;
    float ka[4], kb[4], d[4], se[4], ss[4], Bf[4];
    bool v[4];
    #pragma unroll
    for (int q = 0; q < 4; q++) {
        int n = n0 + q * 256;
        v[q] = n < NM;
        int nn = v[q] ? n : NM - 1;
        ka[q] = alpha[nn] * LOG2E_K;
        kb[q] = beta[nn] * LOG2E_K;
        d[q]  = v[q] ? density[n] : 0.f;
        se[q] = senter[(size_t)c * NM + nn];
        ss[q] = se[q];
        Bf[q] = 1.f;
    }
    __syncthreads();

    int wv = tid >> 6, ln = tid & 63;
    float myval = 0.f;
    float* rp = states + (size_t)c * CH * NM + n0;
    #pragma unroll 1
    for (int j = 0; j < CH; j++) {
        bool live = (Bf[0] != 0.f) | (Bf[1] != 0.f) |
                    (Bf[2] != 0.f) | (Bf[3] != 0.f);
        if (!__any(live)) break;               // wave-uniform exit
        float u = xsl[j];
        float contrib = 0.f;
        #pragma unroll
        for (int q = 0; q < 4; q++) {
            float aa, bb;
            relay_step(ka[q], kb[q], u, aa, bb);
            Bf[q] *= bb;
            ss[q] = fmaf(bb, ss[q], aa);
            if (Bf[q] != 0.f) {                // stored A_t was wrong: fix
                if (v[q]) rp[q * 256] = ss[q];
                contrib = fmaf(d[q] * Bf[q], se[q], contrib);
            }
        }
        rp += NM;
        #pragma unroll
        for (int off = 1; off < 64; off <<= 1)     // butterfly: all lanes
            contrib += __shfl_xor(contrib, off, 64);
        if (ln == j) myval = contrib;
    }
    if (ln < CH)
        partials[(size_t)(NPROW + bx * 4 + wv) * TT + c * CH + ln] = myval;
}

// ---- finalize: fold 80 wave rows + 80 correction rows + 80 densum parts ---
__global__ __launch_bounds__(256) void finalize_kernel(
    const float* __restrict__ x, const float* __restrict__ partials,
    const float* __restrict__ densum_parts,
    const float* __restrict__ msr, const float* __restrict__ mor,
    const float* __restrict__ hsr, float* __restrict__ out)
{
    int t = blockIdx.x * 256 + threadIdx.x;
    if (t >= TT) return;
    float acc = 0.f;
    for (int r = 0; r < NROWS; r++)
        acc += partials[(size_t)r * TT + t];    // coalesced across lanes
    float dsum = 0.f;
    for (int bx = 0; bx < NBLK; bx++)
        dsum += densum_parts[bx];               // uniform -> scalar loads
    float sig_ms = 1.f / (1.f + __expf(-msr[0]));
    float sig_mo = 1.f / (1.f + __expf(-mor[0]));
    float sig_hs = 1.f / (1.f + __expf(-hsr[0]));
    float m_scale  = 10.f * sig_ms;
    float m_offset = fmaf(20.f, sig_mo, -10.f);
    float h_scale  = 10.f * sig_hs;
    float m = acc / dsum;
    out[t] = fmaf(m_scale, m, m_offset) + h_scale * x[t];
}

extern "C" void kernel_launch(void* const* d_in, const int* in_sizes, int n_in,
                              void* d_out, int out_size, void* d_ws, size_t ws_size,
                              hipStream_t stream)
{
    const float* x    = (const float*)d_in[0];   // [4096]
    const float* alpha= (const float*)d_in[1];   // [20301]
    const float* beta = (const float*)d_in[2];   // [20301]
    const float* init = (const float*)d_in[3];   // [20301]
    const float* msr  = (const float*)d_in[4];   // [1]
    const float* mor  = (const float*)d_in[5];   // [1]
    const float* hsr  = (const float*)d_in[6];   // [1]
    const float* w1   = (const float*)d_in[7];
    const float* b1   = (const float*)d_in[8];
    const float* w2   = (const float*)d_in[9];
    const float* b2   = (const float*)d_in[10];
    const float* w3   = (const float*)d_in[11];
    const float* b3   = (const float*)d_in[12];
    const float* w4   = (const float*)d_in[13];
    const float* b4   = (const float*)d_in[14];

    float* out     = (float*)d_out;          // [TT]
    float* density = out + TT;               // [NM]
    float* states  = density + NM;           // [TT*NM]

    // ws: densum_parts[128] | partials[NROWS*TT] | Acomp[NC*NM]
    //   | Bcomp[NC*NM] | senter[NC*NM]          (~34 MB total)
    float* densum_parts = (float*)d_ws;
    float* partials     = densum_parts + 128;
    float* Acomp        = partials + (size_t)NROWS * TT;
    float* Bcomp        = Acomp + (size_t)NC * NM;
    float* senter       = Bcomp + (size_t)NC * NM;

    density_kernel<<<dim3(NBLK), dim3(256), 0, stream>>>(
        alpha, beta, w1, b1, w2, b2, w3, b3, w4, b4,
        density, densum_parts);

    states_spec_kernel<<<dim3(SBLK, NC), dim3(256), 0, stream>>>(
        x, alpha, beta, density, states, partials, Acomp, Bcomp);

    senter_kernel<<<dim3(NBLK), dim3(256), 0, stream>>>(
        init, Acomp, Bcomp, senter);

    patch_kernel<<<dim3(SBLK, NC), dim3(256), 0, stream>>>(
        x, alpha, beta, density, senter, states, partials);

    finalize_kernel<<<dim3(TT / 256), dim3(256), 0, stream>>>(
        x, partials, densum_parts, msr, mor, hsr, out);
}

// Round 5
// 443.262 us; speedup vs baseline: 1.1142x; 1.1142x over previous
//
#include <hip/hip_runtime.h>
#include <math.h>

// Problem constants
#define NM 20301            // mesh points
#define TT 4096             // time steps
#define NC 64               // t-chunks (R5: back to 64 -- R4's 128 regressed)
#define CH 64               // steps per chunk = TT/NC
#define NBLK 80             // 256-thread n-kernels (density / senter)
#define SBLK 20             // states blocks in n (1024 n per block, 4/thread)
#define NPROW (SBLK * 4)    // 80 per-wave partial rows (speculative)
#define NROWS (NPROW + 80)  // + 80 patch correction rows (one per bx,wv)
#define TPH 16              // t-phase width for fused reduce
#define NPH (CH / TPH)      // 4 phases per chunk
#define LOG2E_K 1442.69504f // 1000 * log2(e)  (temp = 0.001)
#define WNEAR 26.0f         // saturation cutoff (|z|>=18 natural units)

// 16-byte vector with 4-byte alignment: NM is odd, so row bases of states/
// Acomp/Bcomp are only dword-aligned. AMDGPU global dwordx4 ops need only
// dword alignment, so this still lowers to one global_store_dwordx4.
typedef float f4 __attribute__((ext_vector_type(4)));
struct __attribute__((packed, aligned(4))) f4u { f4 v; };

// Fused soft-relay step (slow path): one rcp instead of two.
__device__ __forceinline__ void relay_step(float ka, float kb, float ku,
                                           float& aa, float& bb) {
    float z1 = fminf(ka - ku, 63.f);
    float z2 = fminf(ku - kb, 63.f);
    float e1 = __builtin_amdgcn_exp2f(z1);
    float e2 = __builtin_amdgcn_exp2f(z2);
    float p1 = 1.f + e1, p2 = 1.f + e2;
    float r  = __builtin_amdgcn_rcpf(p1 * p2);
    aa = (e2 - e1) * r;
    bb = (e1 * e2) * r;
}

__device__ __forceinline__ float wave_reduce_sum(float w) {
    #pragma unroll
    for (int off = 32; off > 0; off >>= 1)
        w += __shfl_down(w, off, 64);
    return w;
}

// ---------------- density MLP: [N,2] -> 16 -> 16 -> 16 -> 1 ----------------
__global__ __launch_bounds__(256) void density_kernel(
    const float* __restrict__ alpha, const float* __restrict__ beta,
    const float* __restrict__ w1, const float* __restrict__ b1,
    const float* __restrict__ w2, const float* __restrict__ b2,
    const float* __restrict__ w3, const float* __restrict__ b3,
    const float* __restrict__ w4, const float* __restrict__ b4,
    float* __restrict__ density_out, float* __restrict__ densum_parts)
{
    int n = blockIdx.x * 256 + threadIdx.x;
    bool valid = n < NM;
    int nn = valid ? n : NM - 1;
    float a = alpha[nn], b = beta[nn];

    float h1[16], h2[16], h3[16];
    #pragma unroll
    for (int j = 0; j < 16; j++) {
        float v = fmaf(a, w1[j], fmaf(b, w1[16 + j], b1[j]));
        h1[j] = fmaxf(v, 0.f);
    }
    #pragma unroll
    for (int j = 0; j < 16; j++) {
        float v = b2[j];
        #pragma unroll
        for (int k = 0; k < 16; k++) v = fmaf(h1[k], w2[k * 16 + j], v);
        h2[j] = fmaxf(v, 0.f);
    }
    #pragma unroll
    for (int j = 0; j < 16; j++) {
        float v = b3[j];
        #pragma unroll
        for (int k = 0; k < 16; k++) v = fmaf(h2[k], w3[k * 16 + j], v);
        h3[j] = fmaxf(v, 0.f);
    }
    float v = b4[0];
    #pragma unroll
    for (int k = 0; k < 16; k++) v = fmaf(h3[k], w4[k], v);
    float d = 1.f / (1.f + __expf(-v));

    if (valid) density_out[n] = d;
    float wsum = wave_reduce_sum(valid ? d : 0.f);
    __shared__ float ws_[4];
    if ((threadIdx.x & 63) == 0) ws_[threadIdx.x >> 6] = wsum;
    __syncthreads();
    if (threadIdx.x == 0)
        densum_parts[blockIdx.x] = ws_[0] + ws_[1] + ws_[2] + ws_[3];
}

// ---- states pass: speculative affine recurrence, barrier/fence-free -------
// Tracks s_t = A_t + B_t * s_enter with s_enter unknown; B hits exact 0 at
// the first hard saturation, after which states[t] = A_t is final.
// R5 (one change vs R3): each thread owns 4 CONSECUTIVE n, so the per-step
// 4 scalar stores (4 vmcnt entries, 1 KB apart) become ONE dwordx4 store
// (wave writes 1 KB contiguous). Store-issue count and vmcnt pressure /4.
// Fast path (R3-proven) and plain stores retained; R4's NC=128 reverted.
__global__ __launch_bounds__(256) void states_spec_kernel(
    const float* __restrict__ x, const float* __restrict__ alpha,
    const float* __restrict__ beta, const float* __restrict__ density,
    float* __restrict__ states, float* __restrict__ partials,
    float* __restrict__ Acomp, float* __restrict__ Bcomp)
{
    __shared__ float xs[CH];
    __shared__ float tile[4 * 64 * (TPH + 1)];   // 17408 B

    int tid = threadIdx.x;
    int c = blockIdx.y;
    if (tid < CH) xs[tid] = x[c * CH + tid] * LOG2E_K;

    int n0 = blockIdx.x * 1024 + tid * 4;   // 4 consecutive n per thread
    float A[4], B[4], d[4], ka[4], kb[4];
    bool v[4];
    #pragma unroll
    for (int q = 0; q < 4; q++) {
        int n = n0 + q;
        v[q] = n < NM;
        int nn = v[q] ? n : NM - 1;
        ka[q] = alpha[nn] * LOG2E_K;
        kb[q] = beta[nn] * LOG2E_K;
        d[q]  = v[q] ? density[nn] : 0.f;
        A[q] = 0.f; B[q] = 1.f;
    }
    // wave-uniform: every lane's quad fully valid? (false only in the one
    // boundary wave covering n=20300)
    bool wavefull = __all(v[3]);
    __syncthreads();   // once, for xs[]; hot loop below is barrier-free

    int wv = tid >> 6, ln = tid & 63;
    int tl = ln & 15, h = ln >> 4;
    float* wtile = &tile[wv * 64 * (TPH + 1)];
    float* tslot = &wtile[ln * (TPH + 1)];
    float* rp    = states + (size_t)c * CH * NM + n0;
    size_t prow  = (size_t)(blockIdx.x * 4 + wv) * TT + c * CH;

    #pragma unroll 1
    for (int p = 0; p < NPH; p++) {
        float xr[TPH];
        #pragma unroll
        for (int j = 0; j < TPH; j++) xr[j] = xs[p * TPH + j];
        #pragma unroll
        for (int j = 0; j < TPH; j++) {
            float u = xr[j];
            float w1_[4], w2_[4], nr[4];
            #pragma unroll
            for (int q = 0; q < 4; q++) {
                w1_[q] = ka[q] - u;
                w2_[q] = u - kb[q];
                nr[q]  = fminf(fabsf(w1_[q]), fabsf(w2_[q]));
            }
            float nmin = fminf(fminf(nr[0], nr[1]), fminf(nr[2], nr[3]));
            if (__any(nmin < WNEAR)) {           // wave-uniform branch
                #pragma unroll
                for (int q = 0; q < 4; q++) {
                    float aa, bb;
                    relay_step(ka[q], kb[q], u, aa, bb);
                    A[q] = fmaf(bb, A[q], aa);
                    B[q] *= bb;
                }
            } else {
                #pragma unroll
                for (int q = 0; q < 4; q++) {
                    bool su = w1_[q] < 0.f, sd = w2_[q] < 0.f;
                    A[q] = su ? 1.f : (sd ? -1.f : A[q]);
                    B[q] = (su || sd) ? 0.f : B[q];
                }
            }
            if (wavefull) {                      // ONE dwordx4 store
                f4 sv = {A[0], A[1], A[2], A[3]};
                ((f4u*)rp)->v = sv;
            } else {                             // boundary wave only
                #pragma unroll
                for (int q = 0; q < 4; q++)
                    if (v[q]) rp[q] = A[q];
            }
            rp += NM;
            tslot[j] = fmaf(d[0], A[0], fmaf(d[1], A[1],
                       fmaf(d[2], A[2], d[3] * A[3])));
        }
        // wait own LDS writes only (global stores stay in flight)
        asm volatile("s_waitcnt lgkmcnt(0)" ::: "memory");
        float acc = 0.f;
        #pragma unroll
        for (int k = 0; k < TPH; k++)
            acc += wtile[(h * 16 + k) * (TPH + 1) + tl];  // 2-way banks, free
        acc += __shfl_xor(acc, 16, 64);       // fold 4 n-groups
        acc += __shfl_xor(acc, 32, 64);
        if (ln < TPH) partials[prow + p * TPH + ln] = acc;
        // WAR guard before next phase overwrites the tile
        asm volatile("s_waitcnt lgkmcnt(0)" ::: "memory");
    }

    // publish end-of-chunk composite (plain stores; consumed next launch)
    float* ap = Acomp + (size_t)c * NM + n0;
    float* bp = Bcomp + (size_t)c * NM + n0;
    if (wavefull) {
        f4 av = {A[0], A[1], A[2], A[3]};
        f4 bv = {B[0], B[1], B[2], B[3]};
        ((f4u*)ap)->v = av;
        ((f4u*)bp)->v = bv;
    } else {
        #pragma unroll
        for (int q = 0; q < 4; q++)
            if (v[q]) { ap[q] = A[q]; bp[q] = B[q]; }
    }
}

// ---- senter scan: s_enter for every chunk, load-latency-free --------------
// Only the 64-step fmaf chain is serial; the 128 composite loads per thread
// are independent. Batch them in register quarters (16 chunks ahead) so the
// chain never waits on memory. Fully unrolled -> all compile-time indices
// (runtime-indexed register arrays would spill to scratch).
__global__ __launch_bounds__(256) void senter_kernel(
    const float* __restrict__ init_raw,
    const float* __restrict__ Acomp, const float* __restrict__ Bcomp,
    float* __restrict__ senter)
{
    int n = blockIdx.x * 256 + threadIdx.x;
    if (n >= NM) return;
    float s = tanhf(init_raw[n]);
    float a0[16], b0[16], a1[16], b1[16];
    #pragma unroll
    for (int k = 0; k < 16; k++) {
        a0[k] = Acomp[(size_t)k * NM + n];
        b0[k] = Bcomp[(size_t)k * NM + n];
    }
    #pragma unroll
    for (int qtr = 0; qtr < 4; qtr++) {
        if (qtr < 3) {          // prefetch next quarter while chaining this
            #pragma unroll
            for (int k = 0; k < 16; k++) {
                size_t idx = (size_t)((qtr + 1) * 16 + k) * NM + n;
                if (qtr & 1) { a0[k] = Acomp[idx]; b0[k] = Bcomp[idx]; }
                else         { a1[k] = Acomp[idx]; b1[k] = Bcomp[idx]; }
            }
        }
        #pragma unroll
        for (int k = 0; k < 16; k++) {
            senter[(size_t)(qtr * 16 + k) * NM + n] = s;
            if (qtr & 1) s = fmaf(b1[k], s, a1[k]);
            else         s = fmaf(b0[k], s, a0[k]);
        }
    }
}

// ---- patch: parallel prefix fixup, one block per (n-block, chunk) ---------
// 1280 blocks -- no serial chunk loop, no cross-wave atomics. Replays the
// chunk prefix with the exact relay from s_enter until B underflows to
// exact 0 for the whole wave (~8-12 steps), patches states entries that
// were still s_enter-dependent, and keeps the per-step m correction
// (sum_n d*Bf*s_enter) in a per-lane register: after the butterfly reduce,
// lane j keeps step j's value, so the wave's correction row-slice is one
// coalesced store (zeros beyond the break included -- required, ws is
// re-poisoned between iterations).
__global__ __launch_bounds__(256) void patch_kernel(
    const float* __restrict__ x, const float* __restrict__ alpha,
    const float* __restrict__ beta, const float* __restrict__ density,
    const float* __restrict__ senter,
    float* __restrict__ states, float* __restrict__ partials)
{
    __shared__ float xsl[CH];
    int tid = threadIdx.x;
    int c = blockIdx.y, bx = blockIdx.x;
    if (tid < CH) xsl[tid] = x[c * CH + tid] * LOG2E_K;

    int n0 = bx * 1024 + tid;
    float ka[4], kb[4], d[4], se[4], ss[4], Bf[4];
    bool v[4];
    #pragma unroll
    for (int q = 0; q < 4; q++) {
        int n = n0 + q * 256;
        v[q] = n < NM;
        int nn = v[q] ? n : NM - 1;
        ka[q] = alpha[nn] * LOG2E_K;
        kb[q] = beta[nn] * LOG2E_K;
        d[q]  = v[q] ? density[n] : 0.f;
        se[q] = senter[(size_t)c * NM + nn];
        ss[q] = se[q];
        Bf[q] = 1.f;
    }
    __syncthreads();

    int wv = tid >> 6, ln = tid & 63;
    float myval = 0.f;
    float* rp = states + (size_t)c * CH * NM + n0;
    #pragma unroll 1
    for (int j = 0; j < CH; j++) {
        bool live = (Bf[0] != 0.f) | (Bf[1] != 0.f) |
                    (Bf[2] != 0.f) | (Bf[3] != 0.f);
        if (!__any(live)) break;               // wave-uniform exit
        float u = xsl[j];
        float contrib = 0.f;
        #pragma unroll
        for (int q = 0; q < 4; q++) {
            float aa, bb;
            relay_step(ka[q], kb[q], u, aa, bb);
            Bf[q] *= bb;
            ss[q] = fmaf(bb, ss[q], aa);
            if (Bf[q] != 0.f) {                // stored A_t was wrong: fix
                if (v[q]) rp[q * 256] = ss[q];
                contrib = fmaf(d[q] * Bf[q], se[q], contrib);
            }
        }
        rp += NM;
        #pragma unroll
        for (int off = 1; off < 64; off <<= 1)     // butterfly: all lanes
            contrib += __shfl_xor(contrib, off, 64);
        if (ln == j) myval = contrib;
    }
    partials[(size_t)(NPROW + bx * 4 + wv) * TT + c * CH + ln] = myval;
}

// ---- finalize: fold 80 wave rows + 80 correction rows + 80 densum parts ---
__global__ __launch_bounds__(256) void finalize_kernel(
    const float* __restrict__ x, const float* __restrict__ partials,
    const float* __restrict__ densum_parts,
    const float* __restrict__ msr, const float* __restrict__ mor,
    const float* __restrict__ hsr, float* __restrict__ out)
{
    int t = blockIdx.x * 256 + threadIdx.x;
    if (t >= TT) return;
    float acc = 0.f;
    for (int r = 0; r < NROWS; r++)
        acc += partials[(size_t)r * TT + t];    // coalesced across lanes
    float dsum = 0.f;
    for (int bx = 0; bx < NBLK; bx++)
        dsum += densum_parts[bx];               // uniform -> scalar loads
    float sig_ms = 1.f / (1.f + __expf(-msr[0]));
    float sig_mo = 1.f / (1.f + __expf(-mor[0]));
    float sig_hs = 1.f / (1.f + __expf(-hsr[0]));
    float m_scale  = 10.f * sig_ms;
    float m_offset = fmaf(20.f, sig_mo, -10.f);
    float h_scale  = 10.f * sig_hs;
    float m = acc / dsum;
    out[t] = fmaf(m_scale, m, m_offset) + h_scale * x[t];
}

extern "C" void kernel_launch(void* const* d_in, const int* in_sizes, int n_in,
                              void* d_out, int out_size, void* d_ws, size_t ws_size,
                              hipStream_t stream)
{
    const float* x    = (const float*)d_in[0];   // [4096]
    const float* alpha= (const float*)d_in[1];   // [20301]
    const float* beta = (const float*)d_in[2];   // [20301]
    const float* init = (const float*)d_in[3];   // [20301]
    const float* msr  = (const float*)d_in[4];   // [1]
    const float* mor  = (const float*)d_in[5];   // [1]
    const float* hsr  = (const float*)d_in[6];   // [1]
    const float* w1   = (const float*)d_in[7];
    const float* b1   = (const float*)d_in[8];
    const float* w2   = (const float*)d_in[9];
    const float* b2   = (const float*)d_in[10];
    const float* w3   = (const float*)d_in[11];
    const float* b3   = (const float*)d_in[12];
    const float* w4   = (const float*)d_in[13];
    const float* b4   = (const float*)d_in[14];

    float* out     = (float*)d_out;          // [TT]
    float* density = out + TT;               // [NM]
    float* states  = density + NM;           // [TT*NM]

    // ws: densum_parts[128] | partials[NROWS*TT] | Acomp[NC*NM]
    //   | Bcomp[NC*NM] | senter[NC*NM]          (~18.2 MB total)
    float* densum_parts = (float*)d_ws;
    float* partials     = densum_parts + 128;
    float* Acomp        = partials + (size_t)NROWS * TT;
    float* Bcomp        = Acomp + (size_t)NC * NM;
    float* senter       = Bcomp + (size_t)NC * NM;

    density_kernel<<<dim3(NBLK), dim3(256), 0, stream>>>(
        alpha, beta, w1, b1, w2, b2, w3, b3, w4, b4,
        density, densum_parts);

    states_spec_kernel<<<dim3(SBLK, NC), dim3(256), 0, stream>>>(
        x, alpha, beta, density, states, partials, Acomp, Bcomp);

    senter_kernel<<<dim3(NBLK), dim3(256), 0, stream>>>(
        init, Acomp, Bcomp, senter);

    patch_kernel<<<dim3(SBLK, NC), dim3(256), 0, stream>>>(
        x, alpha, beta, density, senter, states, partials);

    finalize_kernel<<<dim3(TT / 256), dim3(256), 0, stream>>>(
        x, partials, densum_parts, msr, mor, hsr, out);
}

// Round 6
// 441.586 us; speedup vs baseline: 1.1184x; 1.0038x over previous
//
#include <hip/hip_runtime.h>
#include <math.h>

// Problem constants
#define NM 20301            // mesh points
#define TT 4096             // time steps
#define NC 64               // t-chunks
#define CH 64               // steps per chunk = TT/NC
#define NBLK 80             // 256-thread n-kernels (density / senter)
#define SBLK 20             // states blocks in n (1024 n per block, 4/thread)
#define NPROW (SBLK * 4)    // 80 per-wave partial rows (speculative)
#define NROWS (NPROW + 80)  // + 80 patch correction rows (one per bx,wv)
#define TPH 16              // t-phase width for fused reduce
#define NPH (CH / TPH)      // 4 phases per chunk
#define LOG2E_K 1442.69504f // 1000 * log2(e)  (temp = 0.001)
#define WNEAR 26.0f         // saturation cutoff (|z|>=18 natural units)

// Fused soft-relay step (slow path): one rcp instead of two.
__device__ __forceinline__ void relay_step(float ka, float kb, float ku,
                                           float& aa, float& bb) {
    float z1 = fminf(ka - ku, 63.f);
    float z2 = fminf(ku - kb, 63.f);
    float e1 = __builtin_amdgcn_exp2f(z1);
    float e2 = __builtin_amdgcn_exp2f(z2);
    float p1 = 1.f + e1, p2 = 1.f + e2;
    float r  = __builtin_amdgcn_rcpf(p1 * p2);
    aa = (e2 - e1) * r;
    bb = (e1 * e2) * r;
}

__device__ __forceinline__ float wave_reduce_sum(float w) {
    #pragma unroll
    for (int off = 32; off > 0; off >>= 1)
        w += __shfl_down(w, off, 64);
    return w;
}

// ---------------- density MLP: [N,2] -> 16 -> 16 -> 16 -> 1 ----------------
__global__ __launch_bounds__(256) void density_kernel(
    const float* __restrict__ alpha, const float* __restrict__ beta,
    const float* __restrict__ w1, const float* __restrict__ b1,
    const float* __restrict__ w2, const float* __restrict__ b2,
    const float* __restrict__ w3, const float* __restrict__ b3,
    const float* __restrict__ w4, const float* __restrict__ b4,
    float* __restrict__ density_out, float* __restrict__ densum_parts)
{
    int n = blockIdx.x * 256 + threadIdx.x;
    bool valid = n < NM;
    int nn = valid ? n : NM - 1;
    float a = alpha[nn], b = beta[nn];

    float h1[16], h2[16], h3[16];
    #pragma unroll
    for (int j = 0; j < 16; j++) {
        float v = fmaf(a, w1[j], fmaf(b, w1[16 + j], b1[j]));
        h1[j] = fmaxf(v, 0.f);
    }
    #pragma unroll
    for (int j = 0; j < 16; j++) {
        float v = b2[j];
        #pragma unroll
        for (int k = 0; k < 16; k++) v = fmaf(h1[k], w2[k * 16 + j], v);
        h2[j] = fmaxf(v, 0.f);
    }
    #pragma unroll
    for (int j = 0; j < 16; j++) {
        float v = b3[j];
        #pragma unroll
        for (int k = 0; k < 16; k++) v = fmaf(h2[k], w3[k * 16 + j], v);
        h3[j] = fmaxf(v, 0.f);
    }
    float v = b4[0];
    #pragma unroll
    for (int k = 0; k < 16; k++) v = fmaf(h3[k], w4[k], v);
    float d = 1.f / (1.f + __expf(-v));

    if (valid) density_out[n] = d;
    float wsum = wave_reduce_sum(valid ? d : 0.f);
    __shared__ float ws_[4];
    if ((threadIdx.x & 63) == 0) ws_[threadIdx.x >> 6] = wsum;
    __syncthreads();
    if (threadIdx.x == 0)
        densum_parts[blockIdx.x] = ws_[0] + ws_[1] + ws_[2] + ws_[3];
}

// ---- states pass: speculative affine recurrence, barrier/fence-free -------
// Tracks s_t = A_t + B_t * s_enter with s_enter unknown; B hits exact 0 at
// the first hard saturation, after which states[t] = A_t is final.
// R6 (one change vs R5): states stores are NON-TEMPORAL. states is a 333 MB
// pure stream-out (never read by any kernel; patch only overwrites a
// prefix). Cache-allocating stores force the 4 MB/XCD L2s to allocate+evict
// the whole stream (~2.1 TB/s observed); nt bypasses allocation, targeting
// the ~5.6 TB/s the harness fill achieves on the same memory.
__global__ __launch_bounds__(256) void states_spec_kernel(
    const float* __restrict__ x, const float* __restrict__ alpha,
    const float* __restrict__ beta, const float* __restrict__ density,
    float* __restrict__ states, float* __restrict__ partials,
    float* __restrict__ Acomp, float* __restrict__ Bcomp)
{
    __shared__ float xs[CH];
    __shared__ float tile[4 * 64 * (TPH + 1)];   // 17408 B

    int tid = threadIdx.x;
    int c = blockIdx.y;
    if (tid < CH) xs[tid] = x[c * CH + tid] * LOG2E_K;

    int n0 = blockIdx.x * 1024 + tid * 4;   // 4 consecutive n per thread
    float A[4], B[4], d[4], ka[4], kb[4];
    bool v[4];
    #pragma unroll
    for (int q = 0; q < 4; q++) {
        int n = n0 + q;
        v[q] = n < NM;
        int nn = v[q] ? n : NM - 1;
        ka[q] = alpha[nn] * LOG2E_K;
        kb[q] = beta[nn] * LOG2E_K;
        d[q]  = v[q] ? density[nn] : 0.f;
        A[q] = 0.f; B[q] = 1.f;
    }
    // wave-uniform: every lane's quad fully valid? (false only in the one
    // boundary wave covering n=20300)
    bool wavefull = __all(v[3]);
    __syncthreads();   // once, for xs[]; hot loop below is barrier-free

    int wv = tid >> 6, ln = tid & 63;
    int tl = ln & 15, h = ln >> 4;
    float* wtile = &tile[wv * 64 * (TPH + 1)];
    float* tslot = &wtile[ln * (TPH + 1)];
    float* rp    = states + (size_t)c * CH * NM + n0;
    size_t prow  = (size_t)(blockIdx.x * 4 + wv) * TT + c * CH;

    #pragma unroll 1
    for (int p = 0; p < NPH; p++) {
        float xr[TPH];
        #pragma unroll
        for (int j = 0; j < TPH; j++) xr[j] = xs[p * TPH + j];
        #pragma unroll
        for (int j = 0; j < TPH; j++) {
            float u = xr[j];
            float w1_[4], w2_[4], nr[4];
            #pragma unroll
            for (int q = 0; q < 4; q++) {
                w1_[q] = ka[q] - u;
                w2_[q] = u - kb[q];
                nr[q]  = fminf(fabsf(w1_[q]), fabsf(w2_[q]));
            }
            float nmin = fminf(fminf(nr[0], nr[1]), fminf(nr[2], nr[3]));
            if (__any(nmin < WNEAR)) {           // wave-uniform branch
                #pragma unroll
                for (int q = 0; q < 4; q++) {
                    float aa, bb;
                    relay_step(ka[q], kb[q], u, aa, bb);
                    A[q] = fmaf(bb, A[q], aa);
                    B[q] *= bb;
                }
            } else {
                #pragma unroll
                for (int q = 0; q < 4; q++) {
                    bool su = w1_[q] < 0.f, sd = w2_[q] < 0.f;
                    A[q] = su ? 1.f : (sd ? -1.f : A[q]);
                    B[q] = (su || sd) ? 0.f : B[q];
                }
            }
            if (wavefull) {                      // 4 consecutive nt dwords
                #pragma unroll
                for (int q = 0; q < 4; q++)
                    __builtin_nontemporal_store(A[q], rp + q);
            } else {                             // boundary wave only
                #pragma unroll
                for (int q = 0; q < 4; q++)
                    if (v[q]) __builtin_nontemporal_store(A[q], rp + q);
            }
            rp += NM;
            tslot[j] = fmaf(d[0], A[0], fmaf(d[1], A[1],
                       fmaf(d[2], A[2], d[3] * A[3])));
        }
        // wait own LDS writes only (global stores stay in flight)
        asm volatile("s_waitcnt lgkmcnt(0)" ::: "memory");
        float acc = 0.f;
        #pragma unroll
        for (int k = 0; k < TPH; k++)
            acc += wtile[(h * 16 + k) * (TPH + 1) + tl];  // 2-way banks, free
        acc += __shfl_xor(acc, 16, 64);       // fold 4 n-groups
        acc += __shfl_xor(acc, 32, 64);
        if (ln < TPH) partials[prow + p * TPH + ln] = acc;
        // WAR guard before next phase overwrites the tile
        asm volatile("s_waitcnt lgkmcnt(0)" ::: "memory");
    }

    // publish end-of-chunk composite (plain cached stores; re-read by the
    // senter/patch kernels soon -> keep L2-allocating)
    float* ap = Acomp + (size_t)c * NM + n0;
    float* bp = Bcomp + (size_t)c * NM + n0;
    #pragma unroll
    for (int q = 0; q < 4; q++) {
        if (v[q]) { ap[q] = A[q]; bp[q] = B[q]; }
    }
}

// ---- senter scan: s_enter for every chunk, load-latency-free --------------
// Only the 64-step fmaf chain is serial; the 128 composite loads per thread
// are independent. Batch them in register quarters (16 chunks ahead) so the
// chain never waits on memory. Fully unrolled -> all compile-time indices
// (runtime-indexed register arrays would spill to scratch).
__global__ __launch_bounds__(256) void senter_kernel(
    const float* __restrict__ init_raw,
    const float* __restrict__ Acomp, const float* __restrict__ Bcomp,
    float* __restrict__ senter)
{
    int n = blockIdx.x * 256 + threadIdx.x;
    if (n >= NM) return;
    float s = tanhf(init_raw[n]);
    float a0[16], b0[16], a1[16], b1[16];
    #pragma unroll
    for (int k = 0; k < 16; k++) {
        a0[k] = Acomp[(size_t)k * NM + n];
        b0[k] = Bcomp[(size_t)k * NM + n];
    }
    #pragma unroll
    for (int qtr = 0; qtr < 4; qtr++) {
        if (qtr < 3) {          // prefetch next quarter while chaining this
            #pragma unroll
            for (int k = 0; k < 16; k++) {
                size_t idx = (size_t)((qtr + 1) * 16 + k) * NM + n;
                if (qtr & 1) { a0[k] = Acomp[idx]; b0[k] = Bcomp[idx]; }
                else         { a1[k] = Acomp[idx]; b1[k] = Bcomp[idx]; }
            }
        }
        #pragma unroll
        for (int k = 0; k < 16; k++) {
            senter[(size_t)(qtr * 16 + k) * NM + n] = s;
            if (qtr & 1) s = fmaf(b1[k], s, a1[k]);
            else         s = fmaf(b0[k], s, a0[k]);
        }
    }
}

// ---- patch: parallel prefix fixup, one block per (n-block, chunk) ---------
// 1280 blocks -- no serial chunk loop, no cross-wave atomics. Replays the
// chunk prefix with the exact relay from s_enter until B underflows to
// exact 0 for the whole wave (~8-12 steps), patches states entries that
// were still s_enter-dependent, and keeps the per-step m correction
// (sum_n d*Bf*s_enter) in a per-lane register: after the butterfly reduce,
// lane j keeps step j's value, so the wave's correction row-slice is one
// coalesced store (zeros beyond the break included -- required, ws is
// re-poisoned between iterations).
__global__ __launch_bounds__(256) void patch_kernel(
    const float* __restrict__ x, const float* __restrict__ alpha,
    const float* __restrict__ beta, const float* __restrict__ density,
    const float* __restrict__ senter,
    float* __restrict__ states, float* __restrict__ partials)
{
    __shared__ float xsl[CH];
    int tid = threadIdx.x;
    int c = blockIdx.y, bx = blockIdx.x;
    if (tid < CH) xsl[tid] = x[c * CH + tid] * LOG2E_K;

    int n0 = bx * 1024 + tid;
    float ka[4], kb[4], d[4], se[4], ss[4], Bf[4];
    bool v[4];
    #pragma unroll
    for (int q = 0; q < 4; q++) {
        int n = n0 + q * 256;
        v[q] = n < NM;
        int nn = v[q] ? n : NM - 1;
        ka[q] = alpha[nn] * LOG2E_K;
        kb[q] = beta[nn] * LOG2E_K;
        d[q]  = v[q] ? density[n] : 0.f;
        se[q] = senter[(size_t)c * NM + nn];
        ss[q] = se[q];
        Bf[q] = 1.f;
    }
    __syncthreads();

    int wv = tid >> 6, ln = tid & 63;
    float myval = 0.f;
    float* rp = states + (size_t)c * CH * NM + n0;
    #pragma unroll 1
    for (int j = 0; j < CH; j++) {
        bool live = (Bf[0] != 0.f) | (Bf[1] != 0.f) |
                    (Bf[2] != 0.f) | (Bf[3] != 0.f);
        if (!__any(live)) break;               // wave-uniform exit
        float u = xsl[j];
        float contrib = 0.f;
        #pragma unroll
        for (int q = 0; q < 4; q++) {
            float aa, bb;
            relay_step(ka[q], kb[q], u, aa, bb);
            Bf[q] *= bb;
            ss[q] = fmaf(bb, ss[q], aa);
            if (Bf[q] != 0.f) {                // stored A_t was wrong: fix
                if (v[q]) rp[q * 256] = ss[q];
                contrib = fmaf(d[q] * Bf[q], se[q], contrib);
            }
        }
        rp += NM;
        #pragma unroll
        for (int off = 1; off < 64; off <<= 1)     // butterfly: all lanes
            contrib += __shfl_xor(contrib, off, 64);
        if (ln == j) myval = contrib;
    }
    partials[(size_t)(NPROW + bx * 4 + wv) * TT + c * CH + ln] = myval;
}

// ---- finalize: fold 80 wave rows + 80 correction rows + 80 densum parts ---
__global__ __launch_bounds__(256) void finalize_kernel(
    const float* __restrict__ x, const float* __restrict__ partials,
    const float* __restrict__ densum_parts,
    const float* __restrict__ msr, const float* __restrict__ mor,
    const float* __restrict__ hsr, float* __restrict__ out)
{
    int t = blockIdx.x * 256 + threadIdx.x;
    if (t >= TT) return;
    float acc = 0.f;
    for (int r = 0; r < NROWS; r++)
        acc += partials[(size_t)r * TT + t];    // coalesced across lanes
    float dsum = 0.f;
    for (int bx = 0; bx < NBLK; bx++)
        dsum += densum_parts[bx];               // uniform -> scalar loads
    float sig_ms = 1.f / (1.f + __expf(-msr[0]));
    float sig_mo = 1.f / (1.f + __expf(-mor[0]));
    float sig_hs = 1.f / (1.f + __expf(-hsr[0]));
    float m_scale  = 10.f * sig_ms;
    float m_offset = fmaf(20.f, sig_mo, -10.f);
    float h_scale  = 10.f * sig_hs;
    float m = acc / dsum;
    out[t] = fmaf(m_scale, m, m_offset) + h_scale * x[t];
}

extern "C" void kernel_launch(void* const* d_in, const int* in_sizes, int n_in,
                              void* d_out, int out_size, void* d_ws, size_t ws_size,
                              hipStream_t stream)
{
    const float* x    = (const float*)d_in[0];   // [4096]
    const float* alpha= (const float*)d_in[1];   // [20301]
    const float* beta = (const float*)d_in[2];   // [20301]
    const float* init = (const float*)d_in[3];   // [20301]
    const float* msr  = (const float*)d_in[4];   // [1]
    const float* mor  = (const float*)d_in[5];   // [1]
    const float* hsr  = (const float*)d_in[6];   // [1]
    const float* w1   = (const float*)d_in[7];
    const float* b1   = (const float*)d_in[8];
    const float* w2   = (const float*)d_in[9];
    const float* b2   = (const float*)d_in[10];
    const float* w3   = (const float*)d_in[11];
    const float* b3   = (const float*)d_in[12];
    const float* w4   = (const float*)d_in[13];
    const float* b4   = (const float*)d_in[14];

    float* out     = (float*)d_out;          // [TT]
    float* density = out + TT;               // [NM]
    float* states  = density + NM;           // [TT*NM]

    // ws: densum_parts[128] | partials[NROWS*TT] | Acomp[NC*NM]
    //   | Bcomp[NC*NM] | senter[NC*NM]          (~18.2 MB total)
    float* densum_parts = (float*)d_ws;
    float* partials     = densum_parts + 128;
    float* Acomp        = partials + (size_t)NROWS * TT;
    float* Bcomp        = Acomp + (size_t)NC * NM;
    float* senter       = Bcomp + (size_t)NC * NM;

    density_kernel<<<dim3(NBLK), dim3(256), 0, stream>>>(
        alpha, beta, w1, b1, w2, b2, w3, b3, w4, b4,
        density, densum_parts);

    states_spec_kernel<<<dim3(SBLK, NC), dim3(256), 0, stream>>>(
        x, alpha, beta, density, states, partials, Acomp, Bcomp);

    senter_kernel<<<dim3(NBLK), dim3(256), 0, stream>>>(
        init, Acomp, Bcomp, senter);

    patch_kernel<<<dim3(SBLK, NC), dim3(256), 0, stream>>>(
        x, alpha, beta, density, senter, states, partials);

    finalize_kernel<<<dim3(TT / 256), dim3(256), 0, stream>>>(
        x, partials, densum_parts, msr, mor, hsr, out);
}

// Round 7
// 436.451 us; speedup vs baseline: 1.1316x; 1.0118x over previous
//
#include <hip/hip_runtime.h>
#include <math.h>

// Problem constants
#define NM 20301            // mesh points
#define TT 4096             // time steps
#define NC 64               // t-chunks
#define CH 64               // steps per chunk = TT/NC
#define NBLK 80             // 256-thread n-kernels (density / senter)
#define SBLK 20             // states blocks in n (1024 n per block, 4/thread)
#define NPROW (SBLK * 4)    // 80 per-wave partial rows (speculative)
#define NROWS (NPROW + 80)  // + 80 patch correction rows (one per bx,wv)
#define TPH 16              // t-phase width for fused reduce
#define NPH (CH / TPH)      // 4 phases per chunk
#define LOG2E_K 1442.69504f // 1000 * log2(e)  (temp = 0.001)
#define WNEAR 26.0f         // saturation cutoff (|z|>=18 natural units)

// 16-byte vector with 4-byte alignment: NM is odd, so row bases of states
// are only dword-aligned. AMDGPU global dwordx4 needs only dword alignment.
typedef float f4 __attribute__((ext_vector_type(4)));
struct __attribute__((packed, aligned(4))) f4u { f4 v; };

// Fused soft-relay step (slow path): one rcp instead of two.
__device__ __forceinline__ void relay_step(float ka, float kb, float ku,
                                           float& aa, float& bb) {
    float z1 = fminf(ka - ku, 63.f);
    float z2 = fminf(ku - kb, 63.f);
    float e1 = __builtin_amdgcn_exp2f(z1);
    float e2 = __builtin_amdgcn_exp2f(z2);
    float p1 = 1.f + e1, p2 = 1.f + e2;
    float r  = __builtin_amdgcn_rcpf(p1 * p2);
    aa = (e2 - e1) * r;
    bb = (e1 * e2) * r;
}

__device__ __forceinline__ float wave_reduce_sum(float w) {
    #pragma unroll
    for (int off = 32; off > 0; off >>= 1)
        w += __shfl_down(w, off, 64);
    return w;
}

// ---------------- density MLP: [N,2] -> 16 -> 16 -> 16 -> 1 ----------------
__global__ __launch_bounds__(256) void density_kernel(
    const float* __restrict__ alpha, const float* __restrict__ beta,
    const float* __restrict__ w1, const float* __restrict__ b1,
    const float* __restrict__ w2, const float* __restrict__ b2,
    const float* __restrict__ w3, const float* __restrict__ b3,
    const float* __restrict__ w4, const float* __restrict__ b4,
    float* __restrict__ density_out, float* __restrict__ densum_parts)
{
    int n = blockIdx.x * 256 + threadIdx.x;
    bool valid = n < NM;
    int nn = valid ? n : NM - 1;
    float a = alpha[nn], b = beta[nn];

    float h1[16], h2[16], h3[16];
    #pragma unroll
    for (int j = 0; j < 16; j++) {
        float v = fmaf(a, w1[j], fmaf(b, w1[16 + j], b1[j]));
        h1[j] = fmaxf(v, 0.f);
    }
    #pragma unroll
    for (int j = 0; j < 16; j++) {
        float v = b2[j];
        #pragma unroll
        for (int k = 0; k < 16; k++) v = fmaf(h1[k], w2[k * 16 + j], v);
        h2[j] = fmaxf(v, 0.f);
    }
    #pragma unroll
    for (int j = 0; j < 16; j++) {
        float v = b3[j];
        #pragma unroll
        for (int k = 0; k < 16; k++) v = fmaf(h2[k], w3[k * 16 + j], v);
        h3[j] = fmaxf(v, 0.f);
    }
    float v = b4[0];
    #pragma unroll
    for (int k = 0; k < 16; k++) v = fmaf(h3[k], w4[k], v);
    float d = 1.f / (1.f + __expf(-v));

    if (valid) density_out[n] = d;
    float wsum = wave_reduce_sum(valid ? d : 0.f);
    __shared__ float ws_[4];
    if ((threadIdx.x & 63) == 0) ws_[threadIdx.x >> 6] = wsum;
    __syncthreads();
    if (threadIdx.x == 0)
        densum_parts[blockIdx.x] = ws_[0] + ws_[1] + ws_[2] + ws_[3];
}

// ---- states pass: speculative affine recurrence, barrier/fence-free -------
// Tracks s_t = A_t + B_t * s_enter with s_enter unknown; B hits exact 0 at
// the first hard saturation, after which states[t] = A_t is final.
// R7 (one change vs R6): per-step stores go through a 4-DEEP ROTATING
// REGISTER STAGING buffer sv[0..3]. Mechanism: a VMEM store reads its data
// register asynchronously; redefining that register requires a protective
// s_waitcnt vmcnt wait. Storing A[q] directly (R0..R6) forces that wait
// EVERY step (A is redefined each step) -- serializing steps at store-read
// latency and explaining VALUBusy~10% / ~2 TB/s effective write BW while
// the harness fill hits 5.6 TB/s (its data reg is never redefined).
// sv[j&3] is redefined only every 4 steps (~1000 cy), with its liveness
// pinned by an empty asm use so the allocator keeps 4 distinct quads.
__global__ __launch_bounds__(256) void states_spec_kernel(
    const float* __restrict__ x, const float* __restrict__ alpha,
    const float* __restrict__ beta, const float* __restrict__ density,
    float* __restrict__ states, float* __restrict__ partials,
    float* __restrict__ Acomp, float* __restrict__ Bcomp)
{
    __shared__ float xs[CH];
    __shared__ float tile[4 * 64 * (TPH + 1)];   // 17408 B

    int tid = threadIdx.x;
    int c = blockIdx.y;
    if (tid < CH) xs[tid] = x[c * CH + tid] * LOG2E_K;

    int n0 = blockIdx.x * 1024 + tid * 4;   // 4 consecutive n per thread
    float A[4], B[4], d[4], ka[4], kb[4];
    bool v[4];
    #pragma unroll
    for (int q = 0; q < 4; q++) {
        int n = n0 + q;
        v[q] = n < NM;
        int nn = v[q] ? n : NM - 1;
        ka[q] = alpha[nn] * LOG2E_K;
        kb[q] = beta[nn] * LOG2E_K;
        d[q]  = v[q] ? density[nn] : 0.f;
        A[q] = 0.f; B[q] = 1.f;
    }
    // wave-uniform: every lane's quad fully valid? (false only in the one
    // boundary wave covering n=20300)
    bool wavefull = __all(v[3]);
    __syncthreads();   // once, for xs[]; hot loop below is barrier-free

    int wv = tid >> 6, ln = tid & 63;
    int tl = ln & 15, h = ln >> 4;
    float* wtile = &tile[wv * 64 * (TPH + 1)];
    float* tslot = &wtile[ln * (TPH + 1)];
    float* rp    = states + (size_t)c * CH * NM + n0;
    size_t prow  = (size_t)(blockIdx.x * 4 + wv) * TT + c * CH;

    // 4-deep rotating store-staging quads (indices below are compile-time:
    // the j-loop is fully unrolled, so sv[j&3] never hits scratch)
    f4 sv[4] = {(f4)0.f, (f4)0.f, (f4)0.f, (f4)0.f};

    #pragma unroll 1
    for (int p = 0; p < NPH; p++) {
        float xr[TPH];
        #pragma unroll
        for (int j = 0; j < TPH; j++) xr[j] = xs[p * TPH + j];
        #pragma unroll
        for (int j = 0; j < TPH; j++) {
            float u = xr[j];
            float w1_[4], w2_[4], nr[4];
            #pragma unroll
            for (int q = 0; q < 4; q++) {
                w1_[q] = ka[q] - u;
                w2_[q] = u - kb[q];
                nr[q]  = fminf(fabsf(w1_[q]), fabsf(w2_[q]));
            }
            float nmin = fminf(fminf(nr[0], nr[1]), fminf(nr[2], nr[3]));
            if (__any(nmin < WNEAR)) {           // wave-uniform branch
                #pragma unroll
                for (int q = 0; q < 4; q++) {
                    float aa, bb;
                    relay_step(ka[q], kb[q], u, aa, bb);
                    A[q] = fmaf(bb, A[q], aa);
                    B[q] *= bb;
                }
            } else {
                #pragma unroll
                for (int q = 0; q < 4; q++) {
                    bool su = w1_[q] < 0.f, sd = w2_[q] < 0.f;
                    A[q] = su ? 1.f : (sd ? -1.f : A[q]);
                    B[q] = (su || sd) ? 0.f : B[q];
                }
            }
            if (wavefull) {
                // keep the PREVIOUS tenant of this slot alive until here:
                // overlapping live ranges force 4 distinct register quads,
                // and the protective vmcnt wait lands 4 steps back.
                asm volatile("" : : "v"(sv[j & 3]));
                f4 t; t[0] = A[0]; t[1] = A[1]; t[2] = A[2]; t[3] = A[3];
                sv[j & 3] = t;
                ((f4u*)rp)->v = sv[j & 3];       // one dwordx4 store
            } else {                             // boundary wave only
                #pragma unroll
                for (int q = 0; q < 4; q++)
                    if (v[q]) rp[q] = A[q];
            }
            rp += NM;
            tslot[j] = fmaf(d[0], A[0], fmaf(d[1], A[1],
                       fmaf(d[2], A[2], d[3] * A[3])));
        }
        // wait own LDS writes only (global stores stay in flight)
        asm volatile("s_waitcnt lgkmcnt(0)" ::: "memory");
        float acc = 0.f;
        #pragma unroll
        for (int k = 0; k < TPH; k++)
            acc += wtile[(h * 16 + k) * (TPH + 1) + tl];  // 2-way banks, free
        acc += __shfl_xor(acc, 16, 64);       // fold 4 n-groups
        acc += __shfl_xor(acc, 32, 64);
        if (ln < TPH) partials[prow + p * TPH + ln] = acc;
        // WAR guard before next phase overwrites the tile
        asm volatile("s_waitcnt lgkmcnt(0)" ::: "memory");
    }

    // publish end-of-chunk composite (plain stores; consumed next launch)
    float* ap = Acomp + (size_t)c * NM + n0;
    float* bp = Bcomp + (size_t)c * NM + n0;
    #pragma unroll
    for (int q = 0; q < 4; q++) {
        if (v[q]) { ap[q] = A[q]; bp[q] = B[q]; }
    }
}

// ---- senter scan: s_enter for every chunk, load-latency-free --------------
// Only the 64-step fmaf chain is serial; the 128 composite loads per thread
// are independent. Batch them in register quarters (16 chunks ahead) so the
// chain never waits on memory. Fully unrolled -> all compile-time indices
// (runtime-indexed register arrays would spill to scratch).
__global__ __launch_bounds__(256) void senter_kernel(
    const float* __restrict__ init_raw,
    const float* __restrict__ Acomp, const float* __restrict__ Bcomp,
    float* __restrict__ senter)
{
    int n = blockIdx.x * 256 + threadIdx.x;
    if (n >= NM) return;
    float s = tanhf(init_raw[n]);
    float a0[16], b0[16], a1[16], b1[16];
    #pragma unroll
    for (int k = 0; k < 16; k++) {
        a0[k] = Acomp[(size_t)k * NM + n];
        b0[k] = Bcomp[(size_t)k * NM + n];
    }
    #pragma unroll
    for (int qtr = 0; qtr < 4; qtr++) {
        if (qtr < 3) {          // prefetch next quarter while chaining this
            #pragma unroll
            for (int k = 0; k < 16; k++) {
                size_t idx = (size_t)((qtr + 1) * 16 + k) * NM + n;
                if (qtr & 1) { a0[k] = Acomp[idx]; b0[k] = Bcomp[idx]; }
                else         { a1[k] = Acomp[idx]; b1[k] = Bcomp[idx]; }
            }
        }
        #pragma unroll
        for (int k = 0; k < 16; k++) {
            senter[(size_t)(qtr * 16 + k) * NM + n] = s;
            if (qtr & 1) s = fmaf(b1[k], s, a1[k]);
            else         s = fmaf(b0[k], s, a0[k]);
        }
    }
}

// ---- patch: parallel prefix fixup, one block per (n-block, chunk) ---------
// 1280 blocks -- no serial chunk loop, no cross-wave atomics. Replays the
// chunk prefix with the exact relay from s_enter until B underflows to
// exact 0 for the whole wave (~8-12 steps), patches states entries that
// were still s_enter-dependent, and keeps the per-step m correction
// (sum_n d*Bf*s_enter) in a per-lane register: after the butterfly reduce,
// lane j keeps step j's value, so the wave's correction row-slice is one
// coalesced store (zeros beyond the break included -- required, ws is
// re-poisoned between iterations).
__global__ __launch_bounds__(256) void patch_kernel(
    const float* __restrict__ x, const float* __restrict__ alpha,
    const float* __restrict__ beta, const float* __restrict__ density,
    const float* __restrict__ senter,
    float* __restrict__ states, float* __restrict__ partials)
{
    __shared__ float xsl[CH];
    int tid = threadIdx.x;
    int c = blockIdx.y, bx = blockIdx.x;
    if (tid < CH) xsl[tid] = x[c * CH + tid] * LOG2E_K;

    int n0 = bx * 1024 + tid;
    float ka[4], kb[4], d[4], se[4], ss[4], Bf[4];
    bool v[4];
    #pragma unroll
    for (int q = 0; q < 4; q++) {
        int n = n0 + q * 256;
        v[q] = n < NM;
        int nn = v[q] ? n : NM - 1;
        ka[q] = alpha[nn] * LOG2E_K;
        kb[q] = beta[nn] * LOG2E_K;
        d[q]  = v[q] ? density[n] : 0.f;
        se[q] = senter[(size_t)c * NM + nn];
        ss[q] = se[q];
        Bf[q] = 1.f;
    }
    __syncthreads();

    int wv = tid >> 6, ln = tid & 63;
    float myval = 0.f;
    float* rp = states + (size_t)c * CH * NM + n0;
    #pragma unroll 1
    for (int j = 0; j < CH; j++) {
        bool live = (Bf[0] != 0.f) | (Bf[1] != 0.f) |
                    (Bf[2] != 0.f) | (Bf[3] != 0.f);
        if (!__any(live)) break;               // wave-uniform exit
        float u = xsl[j];
        float contrib = 0.f;
        #pragma unroll
        for (int q = 0; q < 4; q++) {
            float aa, bb;
            relay_step(ka[q], kb[q], u, aa, bb);
            Bf[q] *= bb;
            ss[q] = fmaf(bb, ss[q], aa);
            if (Bf[q] != 0.f) {                // stored A_t was wrong: fix
                if (v[q]) rp[q * 256] = ss[q];
                contrib = fmaf(d[q] * Bf[q], se[q], contrib);
            }
        }
        rp += NM;
        #pragma unroll
        for (int off = 1; off < 64; off <<= 1)     // butterfly: all lanes
            contrib += __shfl_xor(contrib, off, 64);
        if (ln == j) myval = contrib;
    }
    partials[(size_t)(NPROW + bx * 4 + wv) * TT + c * CH + ln] = myval;
}

// ---- finalize: fold 80 wave rows + 80 correction rows + 80 densum parts ---
__global__ __launch_bounds__(256) void finalize_kernel(
    const float* __restrict__ x, const float* __restrict__ partials,
    const float* __restrict__ densum_parts,
    const float* __restrict__ msr, const float* __restrict__ mor,
    const float* __restrict__ hsr, float* __restrict__ out)
{
    int t = blockIdx.x * 256 + threadIdx.x;
    if (t >= TT) return;
    float acc = 0.f;
    for (int r = 0; r < NROWS; r++)
        acc += partials[(size_t)r * TT + t];    // coalesced across lanes
    float dsum = 0.f;
    for (int bx = 0; bx < NBLK; bx++)
        dsum += densum_parts[bx];               // uniform -> scalar loads
    float sig_ms = 1.f / (1.f + __expf(-msr[0]));
    float sig_mo = 1.f / (1.f + __expf(-mor[0]));
    float sig_hs = 1.f / (1.f + __expf(-hsr[0]));
    float m_scale  = 10.f * sig_ms;
    float m_offset = fmaf(20.f, sig_mo, -10.f);
    float h_scale  = 10.f * sig_hs;
    float m = acc / dsum;
    out[t] = fmaf(m_scale, m, m_offset) + h_scale * x[t];
}

extern "C" void kernel_launch(void* const* d_in, const int* in_sizes, int n_in,
                              void* d_out, int out_size, void* d_ws, size_t ws_size,
                              hipStream_t stream)
{
    const float* x    = (const float*)d_in[0];   // [4096]
    const float* alpha= (const float*)d_in[1];   // [20301]
    const float* beta = (const float*)d_in[2];   // [20301]
    const float* init = (const float*)d_in[3];   // [20301]
    const float* msr  = (const float*)d_in[4];   // [1]
    const float* mor  = (const float*)d_in[5];   // [1]
    const float* hsr  = (const float*)d_in[6];   // [1]
    const float* w1   = (const float*)d_in[7];
    const float* b1   = (const float*)d_in[8];
    const float* w2   = (const float*)d_in[9];
    const float* b2   = (const float*)d_in[10];
    const float* w3   = (const float*)d_in[11];
    const float* b3   = (const float*)d_in[12];
    const float* w4   = (const float*)d_in[13];
    const float* b4   = (const float*)d_in[14];

    float* out     = (float*)d_out;          // [TT]
    float* density = out + TT;               // [NM]
    float* states  = density + NM;           // [TT*NM]

    // ws: densum_parts[128] | partials[NROWS*TT] | Acomp[NC*NM]
    //   | Bcomp[NC*NM] | senter[NC*NM]          (~18.2 MB total)
    float* densum_parts = (float*)d_ws;
    float* partials     = densum_parts + 128;
    float* Acomp        = partials + (size_t)NROWS * TT;
    float* Bcomp        = Acomp + (size_t)NC * NM;
    float* senter       = Bcomp + (size_t)NC * NM;

    density_kernel<<<dim3(NBLK), dim3(256), 0, stream>>>(
        alpha, beta, w1, b1, w2, b2, w3, b3, w4, b4,
        density, densum_parts);

    states_spec_kernel<<<dim3(SBLK, NC), dim3(256), 0, stream>>>(
        x, alpha, beta, density, states, partials, Acomp, Bcomp);

    senter_kernel<<<dim3(NBLK), dim3(256), 0, stream>>>(
        init, Acomp, Bcomp, senter);

    patch_kernel<<<dim3(SBLK, NC), dim3(256), 0, stream>>>(
        x, alpha, beta, density, senter, states, partials);

    finalize_kernel<<<dim3(TT / 256), dim3(256), 0, stream>>>(
        x, partials, densum_parts, msr, mor, hsr, out);
}